// Round 1
// baseline (240.390 us; speedup 1.0000x reference)
//
#include <hip/hip_runtime.h>
#include <math.h>

#define EPS 1e-05

static constexpr int BLOCK = 256;
static constexpr int BPB   = 1024;                     // blocks per batch
static constexpr int NBATCH = 4;
static constexpr long long NPB = 192LL * 192LL * 192LL; // 7,077,888 elems/batch

__device__ __forceinline__ double wave_reduce(double v) {
    #pragma unroll
    for (int off = 32; off > 0; off >>= 1)
        v += __shfl_down(v, off, 64);
    return v;
}

__global__ __launch_bounds__(BLOCK) void ncc_partial(
    const float* __restrict__ y_pred, const float* __restrict__ y_true,
    double* __restrict__ part)
{
    const int b = blockIdx.y;
    const float4* I4 = (const float4*)(y_true + (long long)b * NPB);
    const float4* J4 = (const float4*)(y_pred + (long long)b * NPB);
    const long long n4 = NPB / 4;  // 1,769,472 float4 pairs per batch

    double sI = 0.0, sJ = 0.0, sI2 = 0.0, sJ2 = 0.0, sIJ = 0.0;
    for (long long i = (long long)blockIdx.x * BLOCK + threadIdx.x; i < n4;
         i += (long long)BPB * BLOCK) {
        float4 a = I4[i];
        float4 c = J4[i];
        double i0 = a.x, i1 = a.y, i2 = a.z, i3 = a.w;
        double j0 = c.x, j1 = c.y, j2 = c.z, j3 = c.w;
        sI += (i0 + i1) + (i2 + i3);
        sJ += (j0 + j1) + (j2 + j3);
        sI2 = fma(i0, i0, sI2); sI2 = fma(i1, i1, sI2);
        sI2 = fma(i2, i2, sI2); sI2 = fma(i3, i3, sI2);
        sJ2 = fma(j0, j0, sJ2); sJ2 = fma(j1, j1, sJ2);
        sJ2 = fma(j2, j2, sJ2); sJ2 = fma(j3, j3, sJ2);
        sIJ = fma(i0, j0, sIJ); sIJ = fma(i1, j1, sIJ);
        sIJ = fma(i2, j2, sIJ); sIJ = fma(i3, j3, sIJ);
    }

    sI  = wave_reduce(sI);
    sJ  = wave_reduce(sJ);
    sI2 = wave_reduce(sI2);
    sJ2 = wave_reduce(sJ2);
    sIJ = wave_reduce(sIJ);

    __shared__ double lds[BLOCK / 64][5];
    const int wave = threadIdx.x >> 6;
    const int lane = threadIdx.x & 63;
    if (lane == 0) {
        lds[wave][0] = sI;  lds[wave][1] = sJ;
        lds[wave][2] = sI2; lds[wave][3] = sJ2;
        lds[wave][4] = sIJ;
    }
    __syncthreads();
    if (threadIdx.x == 0) {
        double* p = part + ((long long)b * BPB + blockIdx.x) * 5;
        #pragma unroll
        for (int k = 0; k < 5; ++k)
            p[k] = ((lds[0][k] + lds[1][k]) + (lds[2][k] + lds[3][k]));
    }
}

__global__ __launch_bounds__(BLOCK) void ncc_final(
    const double* __restrict__ part, float* __restrict__ out)
{
    const int b = blockIdx.x;
    double s[5] = {0.0, 0.0, 0.0, 0.0, 0.0};
    for (int i = threadIdx.x; i < BPB; i += BLOCK) {
        const double* p = part + ((long long)b * BPB + i) * 5;
        #pragma unroll
        for (int k = 0; k < 5; ++k) s[k] += p[k];
    }
    #pragma unroll
    for (int k = 0; k < 5; ++k) s[k] = wave_reduce(s[k]);

    __shared__ double lds[BLOCK / 64][5];
    const int wave = threadIdx.x >> 6;
    const int lane = threadIdx.x & 63;
    if (lane == 0) {
        #pragma unroll
        for (int k = 0; k < 5; ++k) lds[wave][k] = s[k];
    }
    __syncthreads();
    if (threadIdx.x == 0) {
        double I_sum = 0, J_sum = 0, I2_sum = 0, J2_sum = 0, IJ_sum = 0;
        #pragma unroll
        for (int w = 0; w < BLOCK / 64; ++w) {
            I_sum  += lds[w][0];
            J_sum  += lds[w][1];
            I2_sum += lds[w][2];
            J2_sum += lds[w][3];
            IJ_sum += lds[w][4];
        }
        const double win = (double)NPB;
        const double u_I = I_sum / win;
        const double u_J = J_sum / win;
        const double cross = IJ_sum - u_J * I_sum - u_I * J_sum + u_I * u_J * win;
        const double I_var = I2_sum - 2.0 * u_I * I_sum + u_I * u_I * win;
        const double J_var = J2_sum - 2.0 * u_J * J_sum + u_J * u_J * win;
        const double cc = cross / (sqrt(I_var) * sqrt(J_var) + EPS);
        out[b] = (float)cc;
    }
}

extern "C" void kernel_launch(void* const* d_in, const int* in_sizes, int n_in,
                              void* d_out, int out_size, void* d_ws, size_t ws_size,
                              hipStream_t stream) {
    // setup_inputs order: y_pred, y_true. reference(y_pred, y_true): Ii=y_true, Ji=y_pred.
    const float* y_pred = (const float*)d_in[0];
    const float* y_true = (const float*)d_in[1];
    float* out = (float*)d_out;
    double* part = (double*)d_ws;   // 4 * 1024 * 5 * 8 B = 160 KB

    dim3 grid1(BPB, NBATCH);
    ncc_partial<<<grid1, BLOCK, 0, stream>>>(y_pred, y_true, part);
    ncc_final<<<NBATCH, BLOCK, 0, stream>>>(part, out);
}

// Round 2
// 236.707 us; speedup vs baseline: 1.0156x; 1.0156x over previous
//
#include <hip/hip_runtime.h>
#include <math.h>

#define EPS 1e-05

static constexpr int BLOCK  = 256;
static constexpr int BPB    = 256;   // blocks per batch
static constexpr int NBATCH = 4;
static constexpr int U      = 3;     // float4s per thread per outer iter
static constexpr int T      = 9;     // outer iterations (exact: 256*256*3*9 = 192^3/4)
static constexpr long long NPB = 192LL * 192LL * 192LL; // 7,077,888 elems/batch

__device__ __forceinline__ double wave_reduce(double v) {
    #pragma unroll
    for (int off = 32; off > 0; off >>= 1)
        v += __shfl_down(v, off, 64);
    return v;
}

__device__ __forceinline__ void acc_pair(const float4& a, const float4& c,
                                         double& sI, double& sJ,
                                         double& sI2, double& sJ2, double& sIJ) {
    double i0 = a.x, i1 = a.y, i2 = a.z, i3 = a.w;
    double j0 = c.x, j1 = c.y, j2 = c.z, j3 = c.w;
    sI += (i0 + i1) + (i2 + i3);
    sJ += (j0 + j1) + (j2 + j3);
    sI2 = fma(i0, i0, sI2); sI2 = fma(i1, i1, sI2);
    sI2 = fma(i2, i2, sI2); sI2 = fma(i3, i3, sI2);
    sJ2 = fma(j0, j0, sJ2); sJ2 = fma(j1, j1, sJ2);
    sJ2 = fma(j2, j2, sJ2); sJ2 = fma(j3, j3, sJ2);
    sIJ = fma(i0, j0, sIJ); sIJ = fma(i1, j1, sIJ);
    sIJ = fma(i2, j2, sIJ); sIJ = fma(i3, j3, sIJ);
}

__global__ __launch_bounds__(BLOCK) void ncc_partial(
    const float* __restrict__ y_pred, const float* __restrict__ y_true,
    double* __restrict__ part)
{
    const int b = blockIdx.y;
    const float4* __restrict__ I4 = (const float4*)(y_true + (long long)b * NPB);
    const float4* __restrict__ J4 = (const float4*)(y_pred + (long long)b * NPB);

    // 32-bit indexing: max float4 index 1,769,471 -> byte offset < 28.4 MB, fits.
    const unsigned base0 = (unsigned)blockIdx.x * (BLOCK * U) + threadIdx.x;
    const unsigned tstride = (unsigned)BPB * BLOCK * U; // 196,608 float4s

    double sI = 0.0, sJ = 0.0, sI2 = 0.0, sJ2 = 0.0, sIJ = 0.0;
    #pragma unroll 1
    for (int t = 0; t < T; ++t) {
        const unsigned idx = base0 + (unsigned)t * tstride;
        // 6 independent coalesced dwordx4 loads in flight per iteration
        float4 a0 = I4[idx];
        float4 a1 = I4[idx + BLOCK];
        float4 a2 = I4[idx + 2 * BLOCK];
        float4 c0 = J4[idx];
        float4 c1 = J4[idx + BLOCK];
        float4 c2 = J4[idx + 2 * BLOCK];
        acc_pair(a0, c0, sI, sJ, sI2, sJ2, sIJ);
        acc_pair(a1, c1, sI, sJ, sI2, sJ2, sIJ);
        acc_pair(a2, c2, sI, sJ, sI2, sJ2, sIJ);
    }

    sI  = wave_reduce(sI);
    sJ  = wave_reduce(sJ);
    sI2 = wave_reduce(sI2);
    sJ2 = wave_reduce(sJ2);
    sIJ = wave_reduce(sIJ);

    __shared__ double lds[BLOCK / 64][5];
    const int wave = threadIdx.x >> 6;
    const int lane = threadIdx.x & 63;
    if (lane == 0) {
        lds[wave][0] = sI;  lds[wave][1] = sJ;
        lds[wave][2] = sI2; lds[wave][3] = sJ2;
        lds[wave][4] = sIJ;
    }
    __syncthreads();
    if (threadIdx.x == 0) {
        double* p = part + ((long long)b * BPB + blockIdx.x) * 5;
        #pragma unroll
        for (int k = 0; k < 5; ++k)
            p[k] = ((lds[0][k] + lds[1][k]) + (lds[2][k] + lds[3][k]));
    }
}

__global__ __launch_bounds__(BLOCK) void ncc_final(
    const double* __restrict__ part, float* __restrict__ out)
{
    const int b = blockIdx.x;
    // One partial set per thread (BPB == BLOCK == 256).
    const double* p = part + ((long long)b * BPB + threadIdx.x) * 5;
    double s[5];
    #pragma unroll
    for (int k = 0; k < 5; ++k) s[k] = p[k];
    #pragma unroll
    for (int k = 0; k < 5; ++k) s[k] = wave_reduce(s[k]);

    __shared__ double lds[BLOCK / 64][5];
    const int wave = threadIdx.x >> 6;
    const int lane = threadIdx.x & 63;
    if (lane == 0) {
        #pragma unroll
        for (int k = 0; k < 5; ++k) lds[wave][k] = s[k];
    }
    __syncthreads();
    if (threadIdx.x == 0) {
        double I_sum  = (lds[0][0] + lds[1][0]) + (lds[2][0] + lds[3][0]);
        double J_sum  = (lds[0][1] + lds[1][1]) + (lds[2][1] + lds[3][1]);
        double I2_sum = (lds[0][2] + lds[1][2]) + (lds[2][2] + lds[3][2]);
        double J2_sum = (lds[0][3] + lds[1][3]) + (lds[2][3] + lds[3][3]);
        double IJ_sum = (lds[0][4] + lds[1][4]) + (lds[2][4] + lds[3][4]);

        const double win = (double)NPB;
        const double u_I = I_sum / win;
        const double u_J = J_sum / win;
        const double cross = IJ_sum - u_J * I_sum - u_I * J_sum + u_I * u_J * win;
        const double I_var = I2_sum - 2.0 * u_I * I_sum + u_I * u_I * win;
        const double J_var = J2_sum - 2.0 * u_J * J_sum + u_J * u_J * win;
        const double cc = cross / (sqrt(I_var) * sqrt(J_var) + EPS);
        out[b] = (float)cc;
    }
}

extern "C" void kernel_launch(void* const* d_in, const int* in_sizes, int n_in,
                              void* d_out, int out_size, void* d_ws, size_t ws_size,
                              hipStream_t stream) {
    // setup_inputs order: y_pred, y_true. reference(y_pred, y_true): Ii=y_true, Ji=y_pred.
    const float* y_pred = (const float*)d_in[0];
    const float* y_true = (const float*)d_in[1];
    float* out = (float*)d_out;
    double* part = (double*)d_ws;   // 4 * 256 * 5 * 8 B = 40 KB

    dim3 grid1(BPB, NBATCH);
    ncc_partial<<<grid1, BLOCK, 0, stream>>>(y_pred, y_true, part);
    ncc_final<<<NBATCH, BLOCK, 0, stream>>>(part, out);
}